// Round 2
// baseline (3800.850 us; speedup 1.0000x reference)
//
#include <hip/hip_runtime.h>
#include <stdint.h>

#define T_SEQ 256
#define B_SZ  64
#define HID   512
#define G4    2048   // 4*HID
#define E_DIM 300
#define E_PAD 320

typedef float f32x4 __attribute__((ext_vector_type(4)));
typedef short bf16x8 __attribute__((ext_vector_type(8)));

__device__ __forceinline__ unsigned short f2bf(float f) {
    union { float f; unsigned u; } v; v.f = f;
    unsigned r = v.u + 0x7FFF + ((v.u >> 16) & 1);   // RNE
    return (unsigned short)(r >> 16);
}
__device__ __forceinline__ float bf2f(unsigned short b) {
    union { unsigned u; float f; } v; v.u = ((unsigned)b) << 16;
    return v.f;
}
__device__ __forceinline__ float sigm(float x) { return 1.0f / (1.0f + expf(-x)); }

// ---------------- diagnostic sentinel (ws too small) ----------------
__global__ void k_sentinel(float* out) { out[0] = 12345.0f; }

// ---------------- embedding gather + cast/pad to bf16 ----------------
__global__ __launch_bounds__(256) void k_gather(const int* __restrict__ ids,
                                                const float* __restrict__ emb,
                                                unsigned short* __restrict__ x) {
    int w = threadIdx.x >> 6, lane = threadIdx.x & 63;
    int row = blockIdx.x * 4 + w;                // 0..16383 (= b*T + t)
    int id = ids[row];
    const float* e = emb + (size_t)id * E_DIM;
    unsigned short* xr = x + (size_t)row * E_PAD;
    for (int k = lane; k < E_PAD; k += 64)
        xr[k] = (k < E_DIM) ? f2bf(e[k]) : (unsigned short)0;
}

// ---------------- fp32 -> bf16 cast with K padding (weights) ----------------
__global__ __launch_bounds__(256) void k_castpad(const float* __restrict__ src,
                                                 unsigned short* __restrict__ dst,
                                                 int Ks, int Kp) {
    int row = blockIdx.x;
    const float* s = src + (size_t)row * Ks;
    unsigned short* d = dst + (size_t)row * Kp;
    for (int k = threadIdx.x; k < Kp; k += 256)
        d[k] = (k < Ks) ? f2bf(s[k]) : (unsigned short)0;
}

// ---------------- bf16 GEMM: pre[t][b][n] = A[m][k] * W[n][k] + bih[n] + bhh[n] ----------------
// A: [16384][Ka] bf16 row-major (m = b*T + t), W: [2048][Ka] bf16 row-major.
// Tile 64x64xBK32, 4 waves, each wave a 16x64 strip.
__global__ __launch_bounds__(256) void k_gemm(const unsigned short* __restrict__ A,
                                              const unsigned short* __restrict__ W,
                                              const float* __restrict__ bih,
                                              const float* __restrict__ bhh,
                                              unsigned short* __restrict__ outp,
                                              int Ka) {
    __shared__ __align__(16) short As[64][40];
    __shared__ __align__(16) short Bs[64][40];
    int tid = threadIdx.x;
    int w = tid >> 6, lane = tid & 63;
    int m0 = blockIdx.x * 64, n0 = blockIdx.y * 64;

    f32x4 acc[4];
    #pragma unroll
    for (int nt = 0; nt < 4; ++nt) { acc[nt][0]=0.f; acc[nt][1]=0.f; acc[nt][2]=0.f; acc[nt][3]=0.f; }

    int r = tid >> 2, seg = tid & 3;
    for (int k0 = 0; k0 < Ka; k0 += 32) {
        *(bf16x8*)&As[r][seg * 8] = *(const bf16x8*)&A[(size_t)(m0 + r) * Ka + k0 + seg * 8];
        *(bf16x8*)&Bs[r][seg * 8] = *(const bf16x8*)&W[(size_t)(n0 + r) * Ka + k0 + seg * 8];
        __syncthreads();
        bf16x8 a = *(const bf16x8*)&As[w * 16 + (lane & 15)][(lane >> 4) * 8];
        #pragma unroll
        for (int nt = 0; nt < 4; ++nt) {
            bf16x8 b = *(const bf16x8*)&Bs[nt * 16 + (lane & 15)][(lane >> 4) * 8];
            acc[nt] = __builtin_amdgcn_mfma_f32_16x16x32_bf16(a, b, acc[nt], 0, 0, 0);
        }
        __syncthreads();
    }
    // D layout: col = lane&15, row = (lane>>4)*4 + reg   [HW-verified]
    #pragma unroll
    for (int nt = 0; nt < 4; ++nt) {
        #pragma unroll
        for (int rr = 0; rr < 4; ++rr) {
            int m = m0 + w * 16 + (lane >> 4) * 4 + rr;
            int col = n0 + nt * 16 + (lane & 15);
            float v = acc[nt][rr] + bih[col] + bhh[col];
            // store as pre[t][b][col]; m = b*256 + t
            outp[((size_t)(m & 255) * B_SZ + (m >> 8)) * G4 + col] = f2bf(v);
        }
    }
}

// ---------------- one LSTM time step, both directions ----------------
// grid: (32 hid-groups, 4 row-groups, 2 dirs), block 256 (4 waves = 4 gates)
// h_pp: bf16 [2][2][64][512]  (ping-pong, dir)
// c_st: fp32 [2][64][512]
__global__ __launch_bounds__(256) void k_lstm_step(
        const unsigned short* __restrict__ pre_f, const unsigned short* __restrict__ pre_b,
        const unsigned short* __restrict__ whh_f, const unsigned short* __restrict__ whh_b,
        unsigned short* __restrict__ h_pp, float* __restrict__ c_st,
        unsigned short* __restrict__ x1,
        unsigned short* __restrict__ h1f, unsigned short* __restrict__ h1b,
        int s, int mode) {
    int tid = threadIdx.x, w = tid >> 6, lane = tid & 63;
    int jg = blockIdx.x, rg = blockIdx.y, dir = blockIdx.z;
    int t = dir ? (T_SEQ - 1 - s) : s;
    int r0 = rg * 16, j0 = jg * 16;
    const unsigned short* pre = dir ? pre_b : pre_f;
    const unsigned short* whh = dir ? whh_b : whh_f;
    const unsigned short* hprev = h_pp + ((size_t)(s & 1) * 2 + dir) * (B_SZ * HID);
    unsigned short* hnext = h_pp + ((size_t)((s + 1) & 1) * 2 + dir) * (B_SZ * HID);

    f32x4 acc; acc[0]=0.f; acc[1]=0.f; acc[2]=0.f; acc[3]=0.f;
    if (s > 0) {
        // A: h tile [16 rows, 512]; B: Whh^T tile [512, 16 gate-cols] for gate w
        const bf16x8* aP = (const bf16x8*)(hprev + (size_t)(r0 + (lane & 15)) * HID + ((lane >> 4) * 8));
        const bf16x8* bP = (const bf16x8*)(whh + (size_t)(w * HID + j0 + (lane & 15)) * HID + ((lane >> 4) * 8));
        #pragma unroll
        for (int kc = 0; kc < 16; ++kc)
            acc = __builtin_amdgcn_mfma_f32_16x16x32_bf16(aP[kc * 4], bP[kc * 4], acc, 0, 0, 0);
    }
    __shared__ float gl[4][16][17];
    #pragma unroll
    for (int rr = 0; rr < 4; ++rr)
        gl[w][(lane >> 4) * 4 + rr][lane & 15] = acc[rr];
    __syncthreads();

    int row = tid >> 4, j = tid & 15;            // 16 batch rows x 16 hidden
    const unsigned short* pb = pre + ((size_t)t * B_SZ + (r0 + row)) * G4 + (j0 + j);
    float iv = gl[0][row][j] + bf2f(pb[0]);
    float fv = gl[1][row][j] + bf2f(pb[512]);
    float gv = gl[2][row][j] + bf2f(pb[1024]);
    float ov = gl[3][row][j] + bf2f(pb[1536]);
    size_t cidx = ((size_t)dir * B_SZ + r0 + row) * HID + j0 + j;
    float cc = (s > 0) ? c_st[cidx] : 0.f;
    cc = sigm(fv) * cc + sigm(iv) * tanhf(gv);
    float hh = sigm(ov) * tanhf(cc);
    c_st[cidx] = cc;
    unsigned short hb = f2bf(hh);
    hnext[(size_t)(r0 + row) * HID + j0 + j] = hb;
    if (mode == 0) {
        // x1[b][t][dir*512 + j]  (row-major for layer-1 GEMM)
        x1[((size_t)(r0 + row) * T_SEQ + t) * 1024 + dir * HID + j0 + j] = hb;
    } else {
        unsigned short* o = dir ? h1b : h1f;     // [t][b][512]
        o[((size_t)t * B_SZ + (r0 + row)) * HID + j0 + j] = hb;
    }
}

// ---------------- scores + per-token masked squared error ----------------
__global__ __launch_bounds__(256) void k_score(const unsigned short* __restrict__ h1f,
                                               const unsigned short* __restrict__ h1b,
                                               const float* __restrict__ lin_w,
                                               const float* __restrict__ lin_b,
                                               const float* __restrict__ labels,
                                               const float* __restrict__ masks,
                                               float* __restrict__ err) {
    int w = threadIdx.x >> 6, lane = threadIdx.x & 63;
    int idx = blockIdx.x * 4 + w;                // 0..16383
    int b = idx >> 8, t = idx & 255;
    size_t base = ((size_t)t * B_SZ + b) * HID + lane * 8;
    bf16x8 hf = *(const bf16x8*)(h1f + base);
    bf16x8 hb = *(const bf16x8*)(h1b + base);
    float sum = 0.f;
    #pragma unroll
    for (int i = 0; i < 8; ++i) {
        float m = 0.5f * (bf2f((unsigned short)hf[i]) + bf2f((unsigned short)hb[i]));
        sum += m * lin_w[lane * 8 + i];
    }
    #pragma unroll
    for (int off = 32; off; off >>= 1) sum += __shfl_xor(sum, off);
    if (lane == 0) {
        float sc = sigm(sum + lin_b[0]);
        float d = sc - labels[b * 256 + t];
        err[b * 256 + t] = d * d * masks[b * 256 + t];
    }
}

// ---------------- final reduction to scalar loss ----------------
__global__ void k_loss(const float* __restrict__ err, const float* __restrict__ masks,
                       float* __restrict__ out) {
    int lane = threadIdx.x;                      // 64 threads, 1 wave
    float se = 0.f, sm = 0.f;
    for (int t = 0; t < 256; ++t) {
        se += err[lane * 256 + t];
        sm += masks[lane * 256 + t];
    }
    float v = se / sm;
    #pragma unroll
    for (int off = 32; off; off >>= 1) v += __shfl_xor(v, off);
    if (lane == 0) out[0] = v * (1.0f / 64.0f);
}

extern "C" void kernel_launch(void* const* d_in, const int* in_sizes, int n_in,
                              void* d_out, int out_size, void* d_ws, size_t ws_size,
                              hipStream_t stream) {
    const int*   ids    = (const int*)d_in[0];
    const float* masks  = (const float*)d_in[1];
    const float* labels = (const float*)d_in[2];
    const float* emb    = (const float*)d_in[3];
    const float* lin_w  = (const float*)d_in[4];
    const float* lin_b  = (const float*)d_in[5];
    // order: 0=l0f, 1=l0b, 2=l1f, 3=l1b
    const float* w_ih[4] = {(const float*)d_in[6],  (const float*)d_in[10],
                            (const float*)d_in[14], (const float*)d_in[18]};
    const float* w_hh[4] = {(const float*)d_in[7],  (const float*)d_in[11],
                            (const float*)d_in[15], (const float*)d_in[19]};
    const float* b_ih[4] = {(const float*)d_in[8],  (const float*)d_in[12],
                            (const float*)d_in[16], (const float*)d_in[20]};
    const float* b_hh[4] = {(const float*)d_in[9],  (const float*)d_in[13],
                            (const float*)d_in[17], (const float*)d_in[21]};

    // ---- workspace layout with lifetime aliasing (≈177 MiB total) ----
    const size_t PRE_B   = (size_t)T_SEQ * B_SZ * G4 * 2;     // 67,108,864
    const size_t SH_B    = (size_t)16384 * 1024 * 2;          // 33,554,432 shared region
    const size_t WHH_B   = (size_t)G4 * HID * 2;              // 2,097,152
    const size_t WT1_B   = (size_t)G4 * 1024 * 2;             // 4,194,304
    const size_t HPP_B   = (size_t)2 * 2 * B_SZ * HID * 2;    // 262,144
    const size_t CST_B   = (size_t)2 * B_SZ * HID * 4;        // 262,144
    const size_t ERR_B   = (size_t)B_SZ * T_SEQ * 4;          // 65,536
    const size_t REQUIRED = 2 * PRE_B + SH_B + 4 * WHH_B + 2 * WT1_B + HPP_B + CST_B + ERR_B;
    if (REQUIRED > ws_size) {                                  // diagnostic sentinel
        k_sentinel<<<1, 1, 0, stream>>>((float*)d_out);
        return;
    }

    char* base = (char*)d_ws;
    unsigned short* pre_f = (unsigned short*)(base);
    unsigned short* pre_b = (unsigned short*)(base + PRE_B);
    char* sh = base + 2 * PRE_B;
    // shared region, phase A-B: x_bf + wt0f + wt0b
    unsigned short* x_bf = (unsigned short*)(sh);
    unsigned short* wt0f = (unsigned short*)(sh + (size_t)16384 * E_PAD * 2);            // +10,485,760
    unsigned short* wt0b = (unsigned short*)(sh + (size_t)16384 * E_PAD * 2 + (size_t)2048 * E_PAD * 2);
    // shared region, phase C-D: x1
    unsigned short* x1   = (unsigned short*)(sh);
    // shared region, phase E-F: h1f + h1b
    unsigned short* h1f  = (unsigned short*)(sh);
    unsigned short* h1b  = (unsigned short*)(sh + (size_t)T_SEQ * B_SZ * HID * 2);       // +16,777,216
    char* q = sh + SH_B;
    unsigned short* whhb[4];
    for (int i = 0; i < 4; ++i) { whhb[i] = (unsigned short*)q; q += WHH_B; }
    unsigned short* wt1f = (unsigned short*)q; q += WT1_B;
    unsigned short* wt1b = (unsigned short*)q; q += WT1_B;
    unsigned short* h_pp = (unsigned short*)q; q += HPP_B;
    float* c_st = (float*)q; q += CST_B;
    float* err  = (float*)q; q += ERR_B;

    // 1. gather + casts
    k_gather<<<4096, 256, 0, stream>>>(ids, emb, x_bf);
    k_castpad<<<2048, 256, 0, stream>>>(w_ih[0], wt0f, E_DIM, E_PAD);
    k_castpad<<<2048, 256, 0, stream>>>(w_ih[1], wt0b, E_DIM, E_PAD);
    k_castpad<<<2048, 256, 0, stream>>>(w_ih[2], wt1f, 1024, 1024);
    k_castpad<<<2048, 256, 0, stream>>>(w_ih[3], wt1b, 1024, 1024);
    for (int i = 0; i < 4; ++i)
        k_castpad<<<2048, 256, 0, stream>>>(w_hh[i], whhb[i], 512, 512);

    dim3 gemm_grid(16384 / 64, 2048 / 64);
    // 2. layer-0 input projections
    k_gemm<<<gemm_grid, 256, 0, stream>>>(x_bf, wt0f, b_ih[0], b_hh[0], pre_f, E_PAD);
    k_gemm<<<gemm_grid, 256, 0, stream>>>(x_bf, wt0b, b_ih[1], b_hh[1], pre_b, E_PAD);

    // 3. layer-0 recurrence (writes x1; x_bf/wt0 dead from here)
    dim3 rec_grid(32, 4, 2);
    for (int s = 0; s < T_SEQ; ++s)
        k_lstm_step<<<rec_grid, 256, 0, stream>>>(pre_f, pre_b, whhb[0], whhb[1],
                                                  h_pp, c_st, x1, nullptr, nullptr, s, 0);

    // 4. layer-1 input projections (pre buffers reused; layer-0 recurrence done)
    k_gemm<<<gemm_grid, 256, 0, stream>>>(x1, wt1f, b_ih[2], b_hh[2], pre_f, 1024);
    k_gemm<<<gemm_grid, 256, 0, stream>>>(x1, wt1b, b_ih[3], b_hh[3], pre_b, 1024);

    // 5. layer-1 recurrence (writes h1f/h1b; x1 dead from here)
    for (int s = 0; s < T_SEQ; ++s)
        k_lstm_step<<<rec_grid, 256, 0, stream>>>(pre_f, pre_b, whhb[2], whhb[3],
                                                  h_pp, c_st, nullptr, h1f, h1b, s, 1);

    // 6. scores + loss
    k_score<<<4096, 256, 0, stream>>>(h1f, h1b, lin_w, lin_b, labels, masks, err);
    k_loss<<<1, 64, 0, stream>>>(err, masks, (float*)d_out);
}